// Round 9
// baseline (567.414 us; speedup 1.0000x reference)
//
#include <hip/hip_runtime.h>

#define FF 512
#define LL 12288
#define NJC 1560   // XB chunk-columns incl. zero pad (max staged col = 1557)
#define NR 128     // XB rows = 16 shifts x 8 batches (only s<8 used by conv_main)

typedef _Float16 half8  __attribute__((ext_vector_type(8)));
typedef float    f32x16 __attribute__((ext_vector_type(16)));

// ---------------- Prologue 1: kernel fp32 -> f16, 32x32x16 A-fragment tiled
// At chunk (ft,kc,lane): elem_j = kernel[ft*32 + (lane&31)][kc*16 + (lane>>5)*8 + j]
__global__ __launch_bounds__(256) void build_At(const float* __restrict__ kern,
                                                _Float16* __restrict__ At) {
    int tid  = blockIdx.x * 256 + threadIdx.x;      // 786432 = 16*768*64
    int lane = tid & 63;
    int rest = tid >> 6;                            // ft*768 + kc
    int kc   = rest % 768;
    int ft   = rest / 768;
    int f    = ft * 32 + (lane & 31);
    int d0   = kc * 16 + (lane >> 5) * 8;
    const float* src = kern + (size_t)f * LL + d0;
    half8 v;
#pragma unroll
    for (int i = 0; i < 8; ++i) v[i] = (_Float16)src[i];
    ((half8*)At)[tid] = v;
}

// ---------------- Prologue 2: B chunk-major layout -------------------------
// XB[jc][r] (16B chunks): r = s*8 + b, s in [0,16). elem_i = x_b[LL-1-(8jc+i)-s]
// (zero when index < 0 -> causal mask, incl. the whole jc >= 1536 pad tail).
__global__ __launch_bounds__(256) void build_XB(const int* __restrict__ ex,
                                                _Float16* __restrict__ XB) {
    int tid = blockIdx.x * 256 + threadIdx.x;       // 199680 = NJC*NR
    int r  = tid & 127;
    int jc = tid >> 7;
    int s  = r >> 3, b = r & 7;
    int j0 = jc * 8;
    half8 v;
#pragma unroll
    for (int i = 0; i < 8; ++i) {
        int idx = LL - 1 - (j0 + i) - s;
        float x = 0.f;
        if (idx >= 0) x = (float)ex[b * LL + idx] * 0.5f - 1.0f;
        v[i] = (_Float16)x;
    }
    ((half8*)XB)[tid] = v;
}

// ---------------- Prologue 3: out = dense_b broadcast ----------------------
__global__ __launch_bounds__(256) void init_out(const float* __restrict__ db,
                                                float* __restrict__ out) {
    int tid = blockIdx.x * 256 + threadIdx.x;       // 393216
    out[tid] = db[tid & 3];
}

__device__ __forceinline__ void gl_lds16(const half8* g, half8* l) {
    __builtin_amdgcn_global_load_lds((const __attribute__((address_space(1))) void*)g,
                                     (__attribute__((address_space(3))) void*)l, 16, 0, 0);
}

// ---------------- Main: all-LDS operands, zero in-loop global loads --------
// Block 128f x 256cols (8b x 32n), 4 waves, wave tile 128x64 = 4(m)x2(n)
// 32x32x16 tiles -> acc 128 AGPR. BK=64 macros (2 K32 substeps, 1 barrier).
// A: 2x16KB LDS dbuf, staged 1 macro ahead. B: 32-column LDS ring (1KB cols
// of XB), staged ~1 macro ahead; live span <= 26 cols. K-loop body is pure
// ds_read+MFMA+VALU; every global_load_lds is >=1 macro old at the barrier
// drain -> no vmcnt stalls anywhere in the loop.
// Tile T=wid*2+ti covers n = n0+4T+nh; QT = LL-1-n0-4T (QT&7 in {3,7} >= nh).
// B frag (tile T, K32 dc, kc16 h): column jc = (QT>>3)+kh+4dc+2h,
//   row (QT&7 - nh)*8 + bb  -> Bring[jc&31][row].
__global__ __launch_bounds__(256, 2) void conv_main(const _Float16* __restrict__ At,
                                                    const _Float16* __restrict__ XB,
                                                    const float* __restrict__ bias,
                                                    const float* __restrict__ dw,
                                                    float* __restrict__ out) {
    __shared__ half8 Abuf[2][4][4][64];   // 32 KB: [buf][kc16][ftl][lane]
    __shared__ half8 Bring[32][64];       // 32 KB: column ring, slot = jc & 31

    int bx    = blockIdx.x;               // 1536 blocks
    int slot  = bx & 7;                   // XCD pin: f_blk per XCD pair
    int f_blk = slot >> 1;                // [0,4)
    int n_blk = 383 - ((bx >> 3) * 2 + (slot & 1));   // largest K first
    int n0 = n_blk << 5;
    int S  = n_blk + 1;                   // true K32 sub-steps
    int M  = (S + 1) >> 1;                // BK=64 macro steps (2 K32 subs each)
    int Q0 = LL - 1 - n0;
    int J0 = (Q0 - 28) >> 3;              // lowest column this block touches

    int tid  = threadIdx.x;
    int lane = tid & 63;
    int wid  = tid >> 6;
    int kh   = lane >> 5;                 // k-half within fragment
    int bb   = lane & 7;
    int nh   = (lane >> 3) & 3;

    const half8* Ag = (const half8*)At;
    const half8* Bg = (const half8*)XB;

    // per-tile fragment constants
    int c0[2], rowi[2];
#pragma unroll
    for (int ti = 0; ti < 2; ++ti) {
        int T  = wid * 2 + ti;
        int QT = Q0 - 4 * T;
        c0[ti]   = (QT >> 3) + kh;                 // column base (+4dc+2h later)
        rowi[ti] = ((QT & 7) - nh) * 8 + bb;       // row within column
    }

    f32x16 acc[4][2];
#pragma unroll
    for (int mt = 0; mt < 4; ++mt)
#pragma unroll
        for (int ti = 0; ti < 2; ++ti)
#pragma unroll
            for (int r = 0; r < 16; ++r) acc[mt][ti][r] = 0.f;

    // ---- prologue staging: A macro 0 -> buf0; B columns [J0, J0+18)
#pragma unroll
    for (int i = 0; i < 4; ++i)
        gl_lds16(Ag + ((size_t)(f_blk * 4 + wid) * 768 + i) * 64 + lane,
                 &Abuf[0][i][wid][lane]);
    for (int c = wid; c < 18; c += 4) {
        int jc = J0 + c;
        gl_lds16(Bg + (size_t)jc * 128 + lane, &Bring[jc & 31][lane]);
    }
    __syncthreads();

    for (int mc = 0; mc < M; ++mc) {
        int buf = mc & 1;
        // stage A for next macro (disjoint buffer)
        if (mc + 1 < M) {
#pragma unroll
            for (int i = 0; i < 4; ++i) {
                int kc = (mc + 1) * 4 + i;
                gl_lds16(Ag + ((size_t)(f_blk * 4 + wid) * 768 + kc) * 64 + lane,
                         &Abuf[buf ^ 1][i][wid][lane]);
            }
        }
        // stage 8 B columns ~1 macro ahead (ring slots disjoint from live span)
        {
            int cb = J0 + 18 + 8 * mc + wid * 2;   // max = 1557 < NJC, pad-safe
            gl_lds16(Bg + (size_t)cb * 128 + lane, &Bring[cb & 31][lane]);
            gl_lds16(Bg + (size_t)(cb + 1) * 128 + lane, &Bring[(cb + 1) & 31][lane]);
        }
#pragma unroll
        for (int sub = 0; sub < 2; ++sub) {
            int dc = mc * 2 + sub;
            half8 af[2][4], bfr[2][2];
#pragma unroll
            for (int h = 0; h < 2; ++h)
#pragma unroll
                for (int mt = 0; mt < 4; ++mt)
                    af[h][mt] = Abuf[buf][sub * 2 + h][mt][lane];
#pragma unroll
            for (int h = 0; h < 2; ++h)
#pragma unroll
                for (int ti = 0; ti < 2; ++ti)
                    bfr[h][ti] = Bring[(c0[ti] + 4 * dc + 2 * h) & 31][rowi[ti]];
#pragma unroll
            for (int h = 0; h < 2; ++h)
#pragma unroll
                for (int mt = 0; mt < 4; ++mt)
#pragma unroll
                    for (int ti = 0; ti < 2; ++ti)
                        acc[mt][ti] = __builtin_amdgcn_mfma_f32_32x32x16_f16(af[h][mt], bfr[h][ti], acc[mt][ti], 0, 0, 0);
        }
        __syncthreads();
    }

    // Epilogue: bias + relu + dense over this block's 128 f rows.
    // C/D 32x32 layout: col = lane&31, row = (reg&3) + 8*(reg>>2) + 4*(lane>>5).
    float p[2][4] = {{0.f}};
#pragma unroll
    for (int mt = 0; mt < 4; ++mt) {
#pragma unroll
        for (int reg = 0; reg < 16; ++reg) {
            int row = (reg & 3) + 8 * (reg >> 2) + 4 * kh;
            int f   = f_blk * 128 + mt * 32 + row;
            float bs = bias[f];
            float4 w = *(const float4*)(dw + (size_t)f * 4);
#pragma unroll
            for (int ti = 0; ti < 2; ++ti) {
                float y = fmaxf(acc[mt][ti][reg] + bs, 0.f);
                p[ti][0] += y * w.x; p[ti][1] += y * w.y;
                p[ti][2] += y * w.z; p[ti][3] += y * w.w;
            }
        }
    }
    // combine the two k-halves (rows differ by 4): lane <-> lane^32
#pragma unroll
    for (int ti = 0; ti < 2; ++ti)
#pragma unroll
        for (int c = 0; c < 4; ++c) {
            float v = p[ti][c];
            v += __shfl_xor(v, 32, 64);
            p[ti][c] = v;
        }
    if (kh == 0) {
#pragma unroll
        for (int ti = 0; ti < 2; ++ti) {
            int n = n0 + (wid * 2 + ti) * 4 + nh;
            float* o = out + ((size_t)bb * LL + n) * 4;
#pragma unroll
            for (int c = 0; c < 4; ++c) atomicAdd(o + c, p[ti][c]);
        }
    }
}

extern "C" void kernel_launch(void* const* d_in, const int* in_sizes, int n_in,
                              void* d_out, int out_size, void* d_ws, size_t ws_size,
                              hipStream_t stream) {
    const int*   ex   = (const int*)d_in[0];
    const float* kern = (const float*)d_in[1];
    const float* bias = (const float*)d_in[2];
    const float* dw   = (const float*)d_in[3];
    const float* db   = (const float*)d_in[4];
    float* out = (float*)d_out;

    _Float16* At = (_Float16*)d_ws;                                   // 12.58 MB
    _Float16* XB = (_Float16*)((char*)d_ws + (size_t)FF * LL * 2);    // +3.19 MB

    hipLaunchKernelGGL(build_At, dim3(3072), dim3(256), 0, stream, kern, At);
    hipLaunchKernelGGL(build_XB, dim3(780),  dim3(256), 0, stream, ex, XB);
    hipLaunchKernelGGL(init_out, dim3(1536), dim3(256), 0, stream, db, out);
    hipLaunchKernelGGL(conv_main, dim3(1536), dim3(256), 0, stream, At, XB, bias, dw, out);
}